// Round 4
// baseline (164.636 us; speedup 1.0000x reference)
//
#include <hip/hip_runtime.h>
#include <math.h>

#define KK 1024
#define DD 64
#define BS 65536              // 2048*32 rows
#define TM 64                 // rows per block
#define NBLK (BS/TM)          // 1024
#define NTHR 512
#define LN_2PI 1.8378770664093453f
#define DECAY 0.9f
#define APAD 136              // LDS row stride in halves (272B, 16B-aligned)

typedef _Float16 f16x8 __attribute__((ext_vector_type(8)));
typedef float f32x16 __attribute__((ext_vector_type(16)));

// ws layout in FLOAT units:
//  [BH_OFF, +65536)  W_hi fp16 [16 kblk][1024 col][8 k]
//  [BL_OFF, +65536)  W_lo fp16 same layout
//  [C_OFF,  +1024)   c[k]
//  [SIG_OFF,+65536)  sigma[k][d] fp32
//  [RESP_OFF,+1024)  resp accumulator
#define BH_OFF   0
#define BL_OFF   65536
#define C_OFF    131072
#define SIG_OFF  (C_OFF + KK)
#define RESP_OFF (SIG_OFF + KK*DD)

__global__ __launch_bounds__(64) void prep_kernel(
    const float* __restrict__ mu, const float* __restrict__ log_sigma,
    float* __restrict__ ws) {
  int k = blockIdx.x;
  int d = threadIdx.x;
  float ls = log_sigma[k*DD + d];
  float m  = mu[k*DD + d];
  float iv = expf(-2.0f*ls);
  _Float16* Bh = (_Float16*)(ws + BH_OFF);
  _Float16* Bl = (_Float16*)(ws + BL_OFF);
  {
    float w0 = -0.5f*iv;                    // coeff of s^2 (dd = d)
    _Float16 hh = (_Float16)w0;
    Bh[((size_t)(d >> 3)*KK + k)*8 + (d & 7)] = hh;
    Bl[((size_t)(d >> 3)*KK + k)*8 + (d & 7)] = (_Float16)(w0 - (float)hh);
  }
  {
    float w1 = m*iv;                        // coeff of s (dd = 64+d)
    _Float16 hh = (_Float16)w1;
    int dd = 64 + d;
    Bh[((size_t)(dd >> 3)*KK + k)*8 + (dd & 7)] = hh;
    Bl[((size_t)(dd >> 3)*KK + k)*8 + (dd & 7)] = (_Float16)(w1 - (float)hh);
  }
  ws[SIG_OFF + k*DD + d] = expf(ls);
  float t1 = m*m*iv;
  float t2 = ls;
  #pragma unroll
  for (int off = 32; off; off >>= 1) {
    t1 += __shfl_xor(t1, off);
    t2 += __shfl_xor(t2, off);
  }
  if (d == 0) ws[C_OFF + k] = -0.5f*t1 - t2 - 32.0f*LN_2PI;
}

// 512 threads = 8 waves. Wave w owns cols [w*128, +128) as 4 coltiles of 32,
// all 64 rows as 2 rowgroups of 32. 32x32x16 MFMA, K=128 in 8 slices of 16.
// B register-double-buffered one slice ahead (the R3 fix: loads issued
// ~810 SIMD-cyc before use, covering L2 latency with zero extra occupancy).
__global__ __launch_bounds__(512, 2) void main_kernel(
    const float* __restrict__ slots, const float* __restrict__ mu,
    const float* __restrict__ z, const float* __restrict__ ws,
    float* __restrict__ out_slots, float* __restrict__ out_ll,
    float* __restrict__ resp_g) {
  __shared__ _Float16 Ah[TM][APAD];   // [row][dd]: dd<64 s^2 hi, dd>=64 s hi
  __shared__ _Float16 Al[TM][APAD];   // lo residuals
  __shared__ float mxl[TM][8];
  __shared__ int   ail[TM][8];
  __shared__ float sml[TM][8];
  __shared__ float gm_l[TM];
  __shared__ float inv_l[TM];
  __shared__ int   am_l[TM];

  const int t    = threadIdx.x;
  const int lane = t & 63;
  const int w    = t >> 6;           // wave = 128-col group
  const int h    = lane >> 5;        // k half (0/1)
  const int lc   = lane & 31;        // col-in-tile (B/C/D) = row-in-tile (A)
  const int R0   = blockIdx.x * TM;

  // ---- stage A as pre-split fp16 hi/lo, row-major ----
  {
    int row = t >> 3;                // 0..63
    int dp  = (t & 7) * 8;           // 0..56
    float4 v0 = *(const float4*)(slots + (size_t)(R0 + row)*DD + dp);
    float4 v1 = *(const float4*)(slots + (size_t)(R0 + row)*DD + dp + 4);
    float f[8] = {v0.x, v0.y, v0.z, v0.w, v1.x, v1.y, v1.z, v1.w};
    f16x8 sqh, sql, sh, sl;
    #pragma unroll
    for (int j = 0; j < 8; ++j) {
      float sq = f[j]*f[j];
      _Float16 h1 = (_Float16)sq;
      sqh[j] = h1; sql[j] = (_Float16)(sq - (float)h1);
      _Float16 h2 = (_Float16)f[j];
      sh[j] = h2;  sl[j]  = (_Float16)(f[j] - (float)h2);
    }
    *(f16x8*)&Ah[row][dp]      = sqh;
    *(f16x8*)&Al[row][dp]      = sql;
    *(f16x8*)&Ah[row][64 + dp] = sh;
    *(f16x8*)&Al[row][64 + dp] = sl;
  }
  __syncthreads();

  // ---- MFMA GEMM with B register double-buffer ----
  const f16x8* BH = (const f16x8*)(ws + BH_OFF);
  const f16x8* BL = (const f16x8*)(ws + BL_OFF);
  const int col0 = (w << 7) + lc;                 // col of ct=0
  const f16x8* pH = BH + (size_t)h*KK + col0;     // + s*2*KK + ct*32
  const f16x8* pL = BL + (size_t)h*KK + col0;

  f32x16 acc[2][4];
  {
    const float* Cc = ws + C_OFF;
    #pragma unroll
    for (int ct = 0; ct < 4; ++ct) {
      float cv = Cc[col0 + ct*32];
      f32x16 ini;
      #pragma unroll
      for (int j = 0; j < 16; ++j) ini[j] = cv;
      acc[0][ct] = ini; acc[1][ct] = ini;
    }
  }

  f16x8 bh[4], bl[4];
  #pragma unroll
  for (int ct = 0; ct < 4; ++ct) { bh[ct] = pH[ct*32]; bl[ct] = pL[ct*32]; }

  #pragma unroll
  for (int s = 0; s < 8; ++s) {
    // A fragments for this slice: lane holds rows lc / 32+lc, k = s*16+h*8..+8
    f16x8 ah0 = *(const f16x8*)&Ah[lc     ][s*16 + h*8];
    f16x8 al0 = *(const f16x8*)&Al[lc     ][s*16 + h*8];
    f16x8 ah1 = *(const f16x8*)&Ah[32 + lc][s*16 + h*8];
    f16x8 al1 = *(const f16x8*)&Al[32 + lc][s*16 + h*8];
    f16x8 nh[4], nl[4];
    if (s < 7) {
      #pragma unroll
      for (int ct = 0; ct < 4; ++ct) {
        nh[ct] = pH[(s+1)*2*KK + ct*32];
        nl[ct] = pL[(s+1)*2*KK + ct*32];
      }
    }
    #pragma unroll
    for (int ct = 0; ct < 4; ++ct) {
      acc[0][ct] = __builtin_amdgcn_mfma_f32_32x32x16_f16(ah0, bh[ct], acc[0][ct], 0, 0, 0);
      acc[1][ct] = __builtin_amdgcn_mfma_f32_32x32x16_f16(ah1, bh[ct], acc[1][ct], 0, 0, 0);
      acc[0][ct] = __builtin_amdgcn_mfma_f32_32x32x16_f16(ah0, bl[ct], acc[0][ct], 0, 0, 0);
      acc[1][ct] = __builtin_amdgcn_mfma_f32_32x32x16_f16(ah1, bl[ct], acc[1][ct], 0, 0, 0);
      acc[0][ct] = __builtin_amdgcn_mfma_f32_32x32x16_f16(al0, bh[ct], acc[0][ct], 0, 0, 0);
      acc[1][ct] = __builtin_amdgcn_mfma_f32_32x32x16_f16(al1, bh[ct], acc[1][ct], 0, 0, 0);
    }
    if (s < 7) {
      #pragma unroll
      for (int ct = 0; ct < 4; ++ct) { bh[ct] = nh[ct]; bl[ct] = nl[ct]; }
    }
  }

  // C/D layout: col = col0 + ct*32, row = rg*32 + (q&3) + 8*(q>>2) + 4*h
  // ---- phase A: per-wave max/argmax over this wave's 128 cols ----
  #pragma unroll
  for (int rg = 0; rg < 2; ++rg) {
    #pragma unroll
    for (int q = 0; q < 16; ++q) {
      float m = acc[rg][0][q];
      int  mi = col0;
      #pragma unroll
      for (int ct = 1; ct < 4; ++ct)
        if (acc[rg][ct][q] > m) { m = acc[rg][ct][q]; mi = col0 + ct*32; }
      #pragma unroll
      for (int off = 1; off < 32; off <<= 1) {
        float om = __shfl_xor(m, off);
        int   oi = __shfl_xor(mi, off);
        if (om > m || (om == m && oi < mi)) { m = om; mi = oi; }
      }
      if (lc == 0) {
        int row = rg*32 + (q&3) + 8*(q>>2) + 4*h;
        mxl[row][w] = m; ail[row][w] = mi;
      }
    }
  }
  __syncthreads();

  // ---- phase B: combine 8 waves -> global max/argmax, ll ----
  if (t < TM) {
    float m = mxl[t][0]; int mi = ail[t][0];
    #pragma unroll
    for (int g = 1; g < 8; ++g) {
      float om = mxl[t][g]; int oi = ail[t][g];
      if (om > m || (om == m && oi < mi)) { m = om; mi = oi; }
    }
    gm_l[t] = m; am_l[t] = mi;
    out_ll[R0 + t] = m;
  }
  __syncthreads();

  // ---- phase F (issue early): new_slots gather loads ----
  const int frow = t >> 3;
  const int fdp  = (t & 7) * 8;
  const int fa   = am_l[frow];
  const float* zr = z  + (size_t)(R0 + frow)*DD + fdp;
  const float* mr = mu + (size_t)fa*DD + fdp;
  const float* sr = ws + SIG_OFF + (size_t)fa*DD + fdp;
  float4 fz0 = *(const float4*)zr,     fz1 = *(const float4*)(zr + 4);
  float4 fm0 = *(const float4*)mr,     fm1 = *(const float4*)(mr + 4);
  float4 fs0 = *(const float4*)sr,     fs1 = *(const float4*)(sr + 4);

  // ---- phase C: exp in place, per-wave exp sums ----
  #pragma unroll
  for (int rg = 0; rg < 2; ++rg) {
    #pragma unroll
    for (int q = 0; q < 16; ++q) {
      int row = rg*32 + (q&3) + 8*(q>>2) + 4*h;
      float gm = gm_l[row];
      float sacc = 0.0f;
      #pragma unroll
      for (int ct = 0; ct < 4; ++ct) {
        float e = __expf(acc[rg][ct][q] - gm);
        acc[rg][ct][q] = e;
        sacc += e;
      }
      #pragma unroll
      for (int off = 1; off < 32; off <<= 1) sacc += __shfl_xor(sacc, off);
      if (lc == 0) sml[row][w] = sacc;
    }
  }
  __syncthreads();
  if (t < TM) {
    float ssum = 0.0f;
    #pragma unroll
    for (int g = 0; g < 8; ++g) ssum += sml[t][g];
    inv_l[t] = 1.0f / ssum;
  }
  __syncthreads();

  // ---- phase E: responsibilities -> direct atomics (wave-owned cols) ----
  {
    float rc[4] = {0.0f, 0.0f, 0.0f, 0.0f};
    #pragma unroll
    for (int rg = 0; rg < 2; ++rg) {
      #pragma unroll
      for (int q = 0; q < 16; ++q) {
        int row = rg*32 + (q&3) + 8*(q>>2) + 4*h;
        float inv = inv_l[row];
        #pragma unroll
        for (int ct = 0; ct < 4; ++ct) rc[ct] += acc[rg][ct][q] * inv;
      }
    }
    #pragma unroll
    for (int ct = 0; ct < 4; ++ct) rc[ct] += __shfl_xor(rc[ct], 32);
    if (lane < 32) {
      #pragma unroll
      for (int ct = 0; ct < 4; ++ct) atomicAdd(resp_g + col0 + ct*32, rc[ct]);
    }
  }

  // ---- phase F finish: new_slots = mu[a] + sigma[a]*z ----
  {
    float4 o0, o1;
    o0.x = fmaf(fs0.x, fz0.x, fm0.x); o0.y = fmaf(fs0.y, fz0.y, fm0.y);
    o0.z = fmaf(fs0.z, fz0.z, fm0.z); o0.w = fmaf(fs0.w, fz0.w, fm0.w);
    o1.x = fmaf(fs1.x, fz1.x, fm1.x); o1.y = fmaf(fs1.y, fz1.y, fm1.y);
    o1.z = fmaf(fs1.z, fz1.z, fm1.z); o1.w = fmaf(fs1.w, fz1.w, fm1.w);
    *(float4*)(out_slots + (size_t)(R0 + frow)*DD + fdp)     = o0;
    *(float4*)(out_slots + (size_t)(R0 + frow)*DD + fdp + 4) = o1;
  }
}

__device__ __forceinline__ float block_max_1024(float v, float* red) {
  #pragma unroll
  for (int off = 32; off; off >>= 1) v = fmaxf(v, __shfl_xor(v, off));
  int wave = threadIdx.x >> 6, lane = threadIdx.x & 63;
  if (lane == 0) red[wave] = v;
  __syncthreads();
  float m = red[0];
  #pragma unroll
  for (int w = 1; w < 16; ++w) m = fmaxf(m, red[w]);
  __syncthreads();
  return m;
}

__device__ __forceinline__ float block_sum_1024(float v, float* red) {
  #pragma unroll
  for (int off = 32; off; off >>= 1) v += __shfl_xor(v, off);
  int wave = threadIdx.x >> 6, lane = threadIdx.x & 63;
  if (lane == 0) red[wave] = v;
  __syncthreads();
  float s = 0.0f;
  #pragma unroll
  for (int w = 0; w < 16; ++w) s += red[w];
  __syncthreads();
  return s;
}

__global__ __launch_bounds__(1024) void finalize_kernel(
    const float* __restrict__ log_prior, const float* __restrict__ resp_g,
    float* __restrict__ out_prior) {
  __shared__ float red[16];
  int t = threadIdx.x;
  float lp = log_prior[t];
  float rs = resp_g[t];

  float m1 = block_max_1024(lp, red);
  float e1 = __expf(lp - m1);
  float s1 = block_sum_1024(e1, red);

  float m2 = block_max_1024(rs, red);
  float e2 = __expf(rs - m2);
  float s2 = block_sum_1024(e2, red);

  out_prior[t] = DECAY * (e1 / s1) + (1.0f - DECAY) * (e2 / s2);
}

extern "C" void kernel_launch(void* const* d_in, const int* in_sizes, int n_in,
                              void* d_out, int out_size, void* d_ws, size_t ws_size,
                              hipStream_t stream) {
  const float* slots     = (const float*)d_in[0];
  const float* mu        = (const float*)d_in[1];
  const float* log_sigma = (const float*)d_in[2];
  const float* log_prior = (const float*)d_in[3];
  const float* z         = (const float*)d_in[4];

  float* out       = (float*)d_out;
  float* out_slots = out;                       // [BS*DD]
  float* out_ll    = out + (size_t)BS*DD;       // [BS]
  float* out_prior = out + (size_t)BS*DD + BS;  // [KK]
  float* ws        = (float*)d_ws;

  hipMemsetAsync(ws + RESP_OFF, 0, KK*sizeof(float), stream);
  prep_kernel<<<KK, 64, 0, stream>>>(mu, log_sigma, ws);
  main_kernel<<<NBLK, NTHR, 0, stream>>>(slots, mu, z, ws, out_slots, out_ll,
                                         ws + RESP_OFF);
  finalize_kernel<<<1, 1024, 0, stream>>>(log_prior, ws + RESP_OFF, out_prior);
}

// Round 5
// 129.932 us; speedup vs baseline: 1.2671x; 1.2671x over previous
//
#include <hip/hip_runtime.h>
#include <math.h>

#define KK 1024
#define DD 64
#define BS 65536              // 2048*32 rows
#define TM 32                 // rows per block
#define NBLK (BS/TM)          // 2048
#define NTHR 512
#define LN_2PI 1.8378770664093453f
#define DECAY 0.9f
#define APAD 136              // LDS row stride in halves (272B, 16B-aligned)

typedef _Float16 f16x8 __attribute__((ext_vector_type(8)));
typedef _Float16 f16x4 __attribute__((ext_vector_type(4)));
typedef float f32x16 __attribute__((ext_vector_type(16)));

// ws layout in FLOAT units:
//  [BH_OFF, +65536)  W_hi fp16 [16 kblk][1024 col][8 k]
//  [BL_OFF, +65536)  W_lo fp16 same layout
//  [C_OFF,  +1024)   c[k]
//  [SIG_OFF,+65536)  sigma[k][d] fp32
//  [RESP_OFF,+1024)  resp accumulator
#define BH_OFF   0
#define BL_OFF   65536
#define C_OFF    131072
#define SIG_OFF  (C_OFF + KK)
#define RESP_OFF (SIG_OFF + KK*DD)

__global__ __launch_bounds__(64) void prep_kernel(
    const float* __restrict__ mu, const float* __restrict__ log_sigma,
    float* __restrict__ ws) {
  int k = blockIdx.x;
  int d = threadIdx.x;
  float ls = log_sigma[k*DD + d];
  float m  = mu[k*DD + d];
  float iv = expf(-2.0f*ls);
  _Float16* Bh = (_Float16*)(ws + BH_OFF);
  _Float16* Bl = (_Float16*)(ws + BL_OFF);
  {
    float w0 = -0.5f*iv;                    // coeff of s^2 (dd = d)
    _Float16 hh = (_Float16)w0;
    Bh[((size_t)(d >> 3)*KK + k)*8 + (d & 7)] = hh;
    Bl[((size_t)(d >> 3)*KK + k)*8 + (d & 7)] = (_Float16)(w0 - (float)hh);
  }
  {
    float w1 = m*iv;                        // coeff of s (dd = 64+d)
    _Float16 hh = (_Float16)w1;
    int dd = 64 + d;
    Bh[((size_t)(dd >> 3)*KK + k)*8 + (dd & 7)] = hh;
    Bl[((size_t)(dd >> 3)*KK + k)*8 + (dd & 7)] = (_Float16)(w1 - (float)hh);
  }
  ws[SIG_OFF + k*DD + d] = expf(ls);
  float t1 = m*m*iv;
  float t2 = ls;
  #pragma unroll
  for (int off = 32; off; off >>= 1) {
    t1 += __shfl_xor(t1, off);
    t2 += __shfl_xor(t2, off);
  }
  if (d == 0) ws[C_OFF + k] = -0.5f*t1 - t2 - 32.0f*LN_2PI;
}

// 512 threads = 8 waves. Wave w owns cols [w*128, +128) as 4 coltiles of 32,
// ALL 32 rows of the block (1 rowgroup). acc = 64 f32/lane -> VGPR <= 128
// -> 4 waves/SIMD = 2 blocks/CU (the R4 fix: occupancy doubles; two blocks
// drift out of phase so barriers/epilogue of one overlap GEMM of the other).
__global__ __launch_bounds__(512, 4) void main_kernel(
    const float* __restrict__ slots, const float* __restrict__ mu,
    const float* __restrict__ z, const float* __restrict__ ws,
    float* __restrict__ out_slots, float* __restrict__ out_ll,
    float* __restrict__ resp_g) {
  __shared__ _Float16 Ah[TM][APAD];   // [row][dd]: dd<64 s^2 hi, dd>=64 s hi
  __shared__ _Float16 Al[TM][APAD];   // lo residuals
  __shared__ float mxl[TM][8];
  __shared__ int   ail[TM][8];
  __shared__ float sml[TM][8];
  __shared__ float gm_l[TM];
  __shared__ float inv_l[TM];
  __shared__ int   am_l[TM];

  const int t    = threadIdx.x;
  const int lane = t & 63;
  const int w    = t >> 6;           // wave = 128-col group
  const int h    = lane >> 5;        // k half (0/1)
  const int lc   = lane & 31;        // col-in-tile (B/C/D) = row-in-tile (A)
  const int R0   = blockIdx.x * TM;

  // ---- stage A as pre-split fp16 hi/lo, row-major ----
  {
    int row = t >> 4;                // 0..31
    int dp  = (t & 15) * 4;          // 0..60
    float4 v = *(const float4*)(slots + (size_t)(R0 + row)*DD + dp);
    float f[4] = {v.x, v.y, v.z, v.w};
    f16x4 sqh, sql, sh, sl;
    #pragma unroll
    for (int j = 0; j < 4; ++j) {
      float sq = f[j]*f[j];
      _Float16 h1 = (_Float16)sq;
      sqh[j] = h1; sql[j] = (_Float16)(sq - (float)h1);
      _Float16 h2 = (_Float16)f[j];
      sh[j] = h2;  sl[j]  = (_Float16)(f[j] - (float)h2);
    }
    *(f16x4*)&Ah[row][dp]      = sqh;
    *(f16x4*)&Al[row][dp]      = sql;
    *(f16x4*)&Ah[row][64 + dp] = sh;
    *(f16x4*)&Al[row][64 + dp] = sl;
  }
  __syncthreads();

  // ---- MFMA GEMM (plain loads; compiler schedules) ----
  const f16x8* BH = (const f16x8*)(ws + BH_OFF);
  const f16x8* BL = (const f16x8*)(ws + BL_OFF);
  const int col0 = (w << 7) + lc;                 // col of ct=0
  const f16x8* pH = BH + (size_t)h*KK + col0;     // + s*2*KK + ct*32
  const f16x8* pL = BL + (size_t)h*KK + col0;

  f32x16 acc[4];
  {
    const float* Cc = ws + C_OFF;
    #pragma unroll
    for (int ct = 0; ct < 4; ++ct) {
      float cv = Cc[col0 + ct*32];
      f32x16 ini;
      #pragma unroll
      for (int j = 0; j < 16; ++j) ini[j] = cv;
      acc[ct] = ini;
    }
  }

  #pragma unroll
  for (int s = 0; s < 8; ++s) {
    // A fragment: lane holds row lc, k = s*16 + h*8 .. +8
    f16x8 ah = *(const f16x8*)&Ah[lc][s*16 + h*8];
    f16x8 al = *(const f16x8*)&Al[lc][s*16 + h*8];
    #pragma unroll
    for (int ct = 0; ct < 4; ++ct) {
      f16x8 bh = pH[(size_t)s*2*KK + ct*32];
      f16x8 bl = pL[(size_t)s*2*KK + ct*32];
      acc[ct] = __builtin_amdgcn_mfma_f32_32x32x16_f16(ah, bh, acc[ct], 0, 0, 0);
      acc[ct] = __builtin_amdgcn_mfma_f32_32x32x16_f16(ah, bl, acc[ct], 0, 0, 0);
      acc[ct] = __builtin_amdgcn_mfma_f32_32x32x16_f16(al, bh, acc[ct], 0, 0, 0);
    }
  }

  // C/D layout: col = col0 + ct*32, row = (q&3) + 8*(q>>2) + 4*h
  // ---- phase A: per-wave max/argmax over this wave's 128 cols ----
  #pragma unroll
  for (int q = 0; q < 16; ++q) {
    float m = acc[0][q];
    int  mi = col0;
    #pragma unroll
    for (int ct = 1; ct < 4; ++ct)
      if (acc[ct][q] > m) { m = acc[ct][q]; mi = col0 + ct*32; }
    #pragma unroll
    for (int off = 1; off < 32; off <<= 1) {
      float om = __shfl_xor(m, off);
      int   oi = __shfl_xor(mi, off);
      if (om > m || (om == m && oi < mi)) { m = om; mi = oi; }
    }
    if (lc == 0) {
      int row = (q&3) + 8*(q>>2) + 4*h;
      mxl[row][w] = m; ail[row][w] = mi;
    }
  }
  __syncthreads();

  // ---- phase B: combine 8 waves -> global max/argmax, ll ----
  if (t < TM) {
    float m = mxl[t][0]; int mi = ail[t][0];
    #pragma unroll
    for (int g = 1; g < 8; ++g) {
      float om = mxl[t][g]; int oi = ail[t][g];
      if (om > m || (om == m && oi < mi)) { m = om; mi = oi; }
    }
    gm_l[t] = m; am_l[t] = mi;
    out_ll[R0 + t] = m;
  }
  __syncthreads();

  // ---- phase F (issue early): new_slots gather loads ----
  const int frow = t >> 4;
  const int fdp  = (t & 15) * 4;
  const int fa   = am_l[frow];
  float4 fz = *(const float4*)(z  + (size_t)(R0 + frow)*DD + fdp);
  float4 fm = *(const float4*)(mu + (size_t)fa*DD + fdp);
  float4 fs = *(const float4*)(ws + SIG_OFF + (size_t)fa*DD + fdp);

  // ---- phase C: exp in place, per-wave exp sums ----
  #pragma unroll
  for (int q = 0; q < 16; ++q) {
    int row = (q&3) + 8*(q>>2) + 4*h;
    float gm = gm_l[row];
    float sacc = 0.0f;
    #pragma unroll
    for (int ct = 0; ct < 4; ++ct) {
      float e = __expf(acc[ct][q] - gm);
      acc[ct][q] = e;
      sacc += e;
    }
    #pragma unroll
    for (int off = 1; off < 32; off <<= 1) sacc += __shfl_xor(sacc, off);
    if (lc == 0) sml[row][w] = sacc;
  }
  __syncthreads();
  if (t < TM) {
    float ssum = 0.0f;
    #pragma unroll
    for (int g = 0; g < 8; ++g) ssum += sml[t][g];
    inv_l[t] = 1.0f / ssum;
  }
  __syncthreads();

  // ---- phase E: responsibilities -> direct atomics (wave-owned cols) ----
  {
    float rc[4] = {0.0f, 0.0f, 0.0f, 0.0f};
    #pragma unroll
    for (int q = 0; q < 16; ++q) {
      int row = (q&3) + 8*(q>>2) + 4*h;
      float inv = inv_l[row];
      #pragma unroll
      for (int ct = 0; ct < 4; ++ct) rc[ct] += acc[ct][q] * inv;
    }
    #pragma unroll
    for (int ct = 0; ct < 4; ++ct) rc[ct] += __shfl_xor(rc[ct], 32);
    if (lane < 32) {
      #pragma unroll
      for (int ct = 0; ct < 4; ++ct) atomicAdd(resp_g + col0 + ct*32, rc[ct]);
    }
  }

  // ---- phase F finish: new_slots = mu[a] + sigma[a]*z ----
  {
    float4 o;
    o.x = fmaf(fs.x, fz.x, fm.x); o.y = fmaf(fs.y, fz.y, fm.y);
    o.z = fmaf(fs.z, fz.z, fm.z); o.w = fmaf(fs.w, fz.w, fm.w);
    *(float4*)(out_slots + (size_t)(R0 + frow)*DD + fdp) = o;
  }
}

__device__ __forceinline__ float block_max_1024(float v, float* red) {
  #pragma unroll
  for (int off = 32; off; off >>= 1) v = fmaxf(v, __shfl_xor(v, off));
  int wave = threadIdx.x >> 6, lane = threadIdx.x & 63;
  if (lane == 0) red[wave] = v;
  __syncthreads();
  float m = red[0];
  #pragma unroll
  for (int w = 1; w < 16; ++w) m = fmaxf(m, red[w]);
  __syncthreads();
  return m;
}

__device__ __forceinline__ float block_sum_1024(float v, float* red) {
  #pragma unroll
  for (int off = 32; off; off >>= 1) v += __shfl_xor(v, off);
  int wave = threadIdx.x >> 6, lane = threadIdx.x & 63;
  if (lane == 0) red[wave] = v;
  __syncthreads();
  float s = 0.0f;
  #pragma unroll
  for (int w = 0; w < 16; ++w) s += red[w];
  __syncthreads();
  return s;
}

__global__ __launch_bounds__(1024) void finalize_kernel(
    const float* __restrict__ log_prior, const float* __restrict__ resp_g,
    float* __restrict__ out_prior) {
  __shared__ float red[16];
  int t = threadIdx.x;
  float lp = log_prior[t];
  float rs = resp_g[t];

  float m1 = block_max_1024(lp, red);
  float e1 = __expf(lp - m1);
  float s1 = block_sum_1024(e1, red);

  float m2 = block_max_1024(rs, red);
  float e2 = __expf(rs - m2);
  float s2 = block_sum_1024(e2, red);

  out_prior[t] = DECAY * (e1 / s1) + (1.0f - DECAY) * (e2 / s2);
}

extern "C" void kernel_launch(void* const* d_in, const int* in_sizes, int n_in,
                              void* d_out, int out_size, void* d_ws, size_t ws_size,
                              hipStream_t stream) {
  const float* slots     = (const float*)d_in[0];
  const float* mu        = (const float*)d_in[1];
  const float* log_sigma = (const float*)d_in[2];
  const float* log_prior = (const float*)d_in[3];
  const float* z         = (const float*)d_in[4];

  float* out       = (float*)d_out;
  float* out_slots = out;                       // [BS*DD]
  float* out_ll    = out + (size_t)BS*DD;       // [BS]
  float* out_prior = out + (size_t)BS*DD + BS;  // [KK]
  float* ws        = (float*)d_ws;

  hipMemsetAsync(ws + RESP_OFF, 0, KK*sizeof(float), stream);
  prep_kernel<<<KK, 64, 0, stream>>>(mu, log_sigma, ws);
  main_kernel<<<NBLK, NTHR, 0, stream>>>(slots, mu, z, ws, out_slots, out_ll,
                                         ws + RESP_OFF);
  finalize_kernel<<<1, 1024, 0, stream>>>(log_prior, ws + RESP_OFF, out_prior);
}

// Round 6
// 115.270 us; speedup vs baseline: 1.4283x; 1.1272x over previous
//
#include <hip/hip_runtime.h>
#include <math.h>

#define KK 1024
#define DD 64
#define BS 65536              // 2048*32 rows
#define TM 32                 // rows per block
#define NBLK (BS/TM)          // 2048
#define NTHR 512
#define LN_2PI 1.8378770664093453f
#define DECAY 0.9f
#define APAD 136              // LDS row stride in halves (272B, 16B-aligned)

typedef _Float16 f16x8 __attribute__((ext_vector_type(8)));
typedef _Float16 f16x4 __attribute__((ext_vector_type(4)));
typedef float f32x16 __attribute__((ext_vector_type(16)));

// ws layout in FLOAT units:
//  [BH_OFF, +65536)  W_hi fp16 [16 kblk][1024 col][8 k]
//  [BL_OFF, +65536)  W_lo fp16 same layout
//  [C_OFF,  +1024)   c[k]
//  [SIG_OFF,+65536)  sigma[k][d] fp32
//  [RESP_OFF,+1024)  resp accumulator
#define BH_OFF   0
#define BL_OFF   65536
#define C_OFF    131072
#define SIG_OFF  (C_OFF + KK)
#define RESP_OFF (SIG_OFF + KK*DD)

__global__ __launch_bounds__(64) void prep_kernel(
    const float* __restrict__ mu, const float* __restrict__ log_sigma,
    float* __restrict__ ws) {
  int k = blockIdx.x;
  int d = threadIdx.x;
  float ls = log_sigma[k*DD + d];
  float m  = mu[k*DD + d];
  float iv = expf(-2.0f*ls);
  _Float16* Bh = (_Float16*)(ws + BH_OFF);
  _Float16* Bl = (_Float16*)(ws + BL_OFF);
  {
    float w0 = -0.5f*iv;                    // coeff of s^2 (dd = d)
    _Float16 hh = (_Float16)w0;
    Bh[((size_t)(d >> 3)*KK + k)*8 + (d & 7)] = hh;
    Bl[((size_t)(d >> 3)*KK + k)*8 + (d & 7)] = (_Float16)(w0 - (float)hh);
  }
  {
    float w1 = m*iv;                        // coeff of s (dd = 64+d)
    _Float16 hh = (_Float16)w1;
    int dd = 64 + d;
    Bh[((size_t)(dd >> 3)*KK + k)*8 + (dd & 7)] = hh;
    Bl[((size_t)(dd >> 3)*KK + k)*8 + (dd & 7)] = (_Float16)(w1 - (float)hh);
  }
  ws[SIG_OFF + k*DD + d] = expf(ls);
  float t1 = m*m*iv;
  float t2 = ls;
  #pragma unroll
  for (int off = 32; off; off >>= 1) {
    t1 += __shfl_xor(t1, off);
    t2 += __shfl_xor(t2, off);
  }
  if (d == 0) ws[C_OFF + k] = -0.5f*t1 - t2 - 32.0f*LN_2PI;
}

// 512 threads = 8 waves. Wave w owns cols [w*128, +128) as 4 coltiles of 32,
// all 32 rows. acc = 64 f32/lane -> 4 waves/SIMD = 2 blocks/CU.
// R6 change: lean epilogue. Max-reduce carries NO index (1 DS + 1 VALU per
// step); argmax recovered afterwards by exact-equality re-scan + one sparse
// LDS atomicMin (max-reduce is arithmetic-free, so gm is bit-identical to
// the winning element; min col == first index == jnp.argmax tie-break).
__global__ __launch_bounds__(512, 4) void main_kernel(
    const float* __restrict__ slots, const float* __restrict__ mu,
    const float* __restrict__ z, const float* __restrict__ ws,
    float* __restrict__ out_slots, float* __restrict__ out_ll,
    float* __restrict__ resp_g) {
  __shared__ _Float16 Ah[TM][APAD];   // [row][dd]: dd<64 s^2 hi, dd>=64 s hi
  __shared__ _Float16 Al[TM][APAD];   // lo residuals
  __shared__ float mxl[TM][8];        // per-(row,wave) partial max
  __shared__ float sml[TM][8];        // per-(row,wave) partial exp-sum
  __shared__ float gm_l[TM];
  __shared__ float inv_l[TM];
  __shared__ int   am_l[TM];

  const int t    = threadIdx.x;
  const int lane = t & 63;
  const int w    = t >> 6;           // wave = 128-col group
  const int h    = lane >> 5;        // k half (0/1)
  const int lc   = lane & 31;        // col-in-tile (B/C/D) = row-in-tile (A)
  const int R0   = blockIdx.x * TM;

  // ---- stage A as pre-split fp16 hi/lo, row-major ----
  {
    int row = t >> 4;                // 0..31
    int dp  = (t & 15) * 4;          // 0..60
    float4 v = *(const float4*)(slots + (size_t)(R0 + row)*DD + dp);
    float f[4] = {v.x, v.y, v.z, v.w};
    f16x4 sqh, sql, sh, sl;
    #pragma unroll
    for (int j = 0; j < 4; ++j) {
      float sq = f[j]*f[j];
      _Float16 h1 = (_Float16)sq;
      sqh[j] = h1; sql[j] = (_Float16)(sq - (float)h1);
      _Float16 h2 = (_Float16)f[j];
      sh[j] = h2;  sl[j]  = (_Float16)(f[j] - (float)h2);
    }
    *(f16x4*)&Ah[row][dp]      = sqh;
    *(f16x4*)&Al[row][dp]      = sql;
    *(f16x4*)&Ah[row][64 + dp] = sh;
    *(f16x4*)&Al[row][64 + dp] = sl;
  }
  if (t < TM) am_l[t] = 0x7fffffff;
  __syncthreads();

  // ---- MFMA GEMM (plain loads; compiler schedules) ----
  const f16x8* BH = (const f16x8*)(ws + BH_OFF);
  const f16x8* BL = (const f16x8*)(ws + BL_OFF);
  const int col0 = (w << 7) + lc;                 // col of ct=0
  const f16x8* pH = BH + (size_t)h*KK + col0;     // + s*2*KK + ct*32
  const f16x8* pL = BL + (size_t)h*KK + col0;

  f32x16 acc[4];
  {
    const float* Cc = ws + C_OFF;
    #pragma unroll
    for (int ct = 0; ct < 4; ++ct) {
      float cv = Cc[col0 + ct*32];
      f32x16 ini;
      #pragma unroll
      for (int j = 0; j < 16; ++j) ini[j] = cv;
      acc[ct] = ini;
    }
  }

  #pragma unroll
  for (int s = 0; s < 8; ++s) {
    // A fragment: lane holds row lc, k = s*16 + h*8 .. +8
    f16x8 ah = *(const f16x8*)&Ah[lc][s*16 + h*8];
    f16x8 al = *(const f16x8*)&Al[lc][s*16 + h*8];
    #pragma unroll
    for (int ct = 0; ct < 4; ++ct) {
      f16x8 bh = pH[(size_t)s*2*KK + ct*32];
      f16x8 bl = pL[(size_t)s*2*KK + ct*32];
      acc[ct] = __builtin_amdgcn_mfma_f32_32x32x16_f16(ah, bh, acc[ct], 0, 0, 0);
      acc[ct] = __builtin_amdgcn_mfma_f32_32x32x16_f16(ah, bl, acc[ct], 0, 0, 0);
      acc[ct] = __builtin_amdgcn_mfma_f32_32x32x16_f16(al, bh, acc[ct], 0, 0, 0);
    }
  }

  // C/D layout: col = col0 + ct*32, row = (q&3) + 8*(q>>2) + 4*h
  // ---- phase A: per-wave MAX ONLY (no index) ----
  #pragma unroll
  for (int q = 0; q < 16; ++q) {
    float m = fmaxf(fmaxf(acc[0][q], acc[1][q]), fmaxf(acc[2][q], acc[3][q]));
    #pragma unroll
    for (int off = 1; off < 32; off <<= 1)
      m = fmaxf(m, __shfl_xor(m, off));
    if (lc == 0) mxl[(q&3) + 8*(q>>2) + 4*h][w] = m;
  }
  __syncthreads();

  // ---- phase B: combine 8 waves -> global max, ll ----
  if (t < TM) {
    float m = mxl[t][0];
    #pragma unroll
    for (int g = 1; g < 8; ++g) m = fmaxf(m, mxl[t][g]);
    gm_l[t] = m;
    out_ll[R0 + t] = m;
  }
  __syncthreads();

  // ---- phase C: argmax eq-scan + sparse atomicMin; exp in place; sums ----
  #pragma unroll
  for (int q = 0; q < 16; ++q) {
    const int row = (q&3) + 8*(q>>2) + 4*h;
    const float gm = gm_l[row];
    // eq-scan, descending ct so final cand = smallest matching col
    int cand = 0x7fffffff;
    #pragma unroll
    for (int ct = 3; ct >= 0; --ct)
      if (acc[ct][q] == gm) cand = col0 + ct*32;
    if (cand != 0x7fffffff) atomicMin(&am_l[row], cand);
    float sacc = 0.0f;
    #pragma unroll
    for (int ct = 0; ct < 4; ++ct) {
      float e = __expf(acc[ct][q] - gm);
      acc[ct][q] = e;
      sacc += e;
    }
    #pragma unroll
    for (int off = 1; off < 32; off <<= 1) sacc += __shfl_xor(sacc, off);
    if (lc == 0) sml[row][w] = sacc;
  }
  __syncthreads();
  if (t < TM) {
    float ssum = 0.0f;
    #pragma unroll
    for (int g = 0; g < 8; ++g) ssum += sml[t][g];
    inv_l[t] = 1.0f / ssum;
  }
  __syncthreads();

  // ---- phase E: responsibilities -> direct atomics (wave-owned cols) ----
  {
    float rc[4] = {0.0f, 0.0f, 0.0f, 0.0f};
    #pragma unroll
    for (int q = 0; q < 16; ++q) {
      int row = (q&3) + 8*(q>>2) + 4*h;
      float inv = inv_l[row];
      #pragma unroll
      for (int ct = 0; ct < 4; ++ct) rc[ct] += acc[ct][q] * inv;
    }
    #pragma unroll
    for (int ct = 0; ct < 4; ++ct) rc[ct] += __shfl_xor(rc[ct], 32);
    if (lane < 32) {
      #pragma unroll
      for (int ct = 0; ct < 4; ++ct) atomicAdd(resp_g + col0 + ct*32, rc[ct]);
    }
  }

  // ---- phase F: new_slots = mu[a] + sigma[a]*z (am_l final after barrier) ----
  {
    const int frow = t >> 4;
    const int fdp  = (t & 15) * 4;
    const int fa   = am_l[frow];
    float4 fz = *(const float4*)(z  + (size_t)(R0 + frow)*DD + fdp);
    float4 fm = *(const float4*)(mu + (size_t)fa*DD + fdp);
    float4 fs = *(const float4*)(ws + SIG_OFF + (size_t)fa*DD + fdp);
    float4 o;
    o.x = fmaf(fs.x, fz.x, fm.x); o.y = fmaf(fs.y, fz.y, fm.y);
    o.z = fmaf(fs.z, fz.z, fm.z); o.w = fmaf(fs.w, fz.w, fm.w);
    *(float4*)(out_slots + (size_t)(R0 + frow)*DD + fdp) = o;
  }
}

__device__ __forceinline__ float block_max_1024(float v, float* red) {
  #pragma unroll
  for (int off = 32; off; off >>= 1) v = fmaxf(v, __shfl_xor(v, off));
  int wave = threadIdx.x >> 6, lane = threadIdx.x & 63;
  if (lane == 0) red[wave] = v;
  __syncthreads();
  float m = red[0];
  #pragma unroll
  for (int w = 1; w < 16; ++w) m = fmaxf(m, red[w]);
  __syncthreads();
  return m;
}

__device__ __forceinline__ float block_sum_1024(float v, float* red) {
  #pragma unroll
  for (int off = 32; off; off >>= 1) v += __shfl_xor(v, off);
  int wave = threadIdx.x >> 6, lane = threadIdx.x & 63;
  if (lane == 0) red[wave] = v;
  __syncthreads();
  float s = 0.0f;
  #pragma unroll
  for (int w = 0; w < 16; ++w) s += red[w];
  __syncthreads();
  return s;
}

__global__ __launch_bounds__(1024) void finalize_kernel(
    const float* __restrict__ log_prior, const float* __restrict__ resp_g,
    float* __restrict__ out_prior) {
  __shared__ float red[16];
  int t = threadIdx.x;
  float lp = log_prior[t];
  float rs = resp_g[t];

  float m1 = block_max_1024(lp, red);
  float e1 = __expf(lp - m1);
  float s1 = block_sum_1024(e1, red);

  float m2 = block_max_1024(rs, red);
  float e2 = __expf(rs - m2);
  float s2 = block_sum_1024(e2, red);

  out_prior[t] = DECAY * (e1 / s1) + (1.0f - DECAY) * (e2 / s2);
}

extern "C" void kernel_launch(void* const* d_in, const int* in_sizes, int n_in,
                              void* d_out, int out_size, void* d_ws, size_t ws_size,
                              hipStream_t stream) {
  const float* slots     = (const float*)d_in[0];
  const float* mu        = (const float*)d_in[1];
  const float* log_sigma = (const float*)d_in[2];
  const float* log_prior = (const float*)d_in[3];
  const float* z         = (const float*)d_in[4];

  float* out       = (float*)d_out;
  float* out_slots = out;                       // [BS*DD]
  float* out_ll    = out + (size_t)BS*DD;       // [BS]
  float* out_prior = out + (size_t)BS*DD + BS;  // [KK]
  float* ws        = (float*)d_ws;

  hipMemsetAsync(ws + RESP_OFF, 0, KK*sizeof(float), stream);
  prep_kernel<<<KK, 64, 0, stream>>>(mu, log_sigma, ws);
  main_kernel<<<NBLK, NTHR, 0, stream>>>(slots, mu, z, ws, out_slots, out_ll,
                                         ws + RESP_OFF);
  finalize_kernel<<<1, 1024, 0, stream>>>(log_prior, ws + RESP_OFF, out_prior);
}